// Round 14
// baseline (4865.441 us; speedup 1.0000x reference)
//
#include <hip/hip_runtime.h>
#include <math.h>

// B=16, T=512, F=512, H=8, D=64; rows = B*T = 8192
#define GRID_WGS 64   // launched WGs for GRU (512 thr each); 4 elected (same XCD) participate

typedef __attribute__((ext_vector_type(8))) short bf16x8;
typedef __attribute__((ext_vector_type(4))) float f32x4;
typedef __attribute__((ext_vector_type(4))) unsigned short us4;

static __device__ __forceinline__ float sigmoidf_(float x) {
    return 1.0f / (1.0f + __expf(-x));
}
static __device__ __forceinline__ unsigned short f2bf(float f) {
    unsigned int u = __float_as_uint(f);
    u += 0x7fffu + ((u >> 16) & 1u);
    return (unsigned short)(u >> 16);
}
static __device__ __forceinline__ float bfbits2f(unsigned int b) {
    return __uint_as_float(b << 16);
}
static __device__ __forceinline__ void gload_lds16(const void* g, void* l) {
    __builtin_amdgcn_global_load_lds(
        (const __attribute__((address_space(1))) unsigned int*)g,
        (__attribute__((address_space(3))) unsigned int*)l, 16, 0, 0);
}

// ---------------- prep: f2bf(x) + bias concat + 6 weight transposes + zero hbuf/Z -------------
__global__ __launch_bounds__(256)
void prep(const float* __restrict__ x, unsigned short* __restrict__ xb,
          const float* __restrict__ bq, const float* __restrict__ bk,
          const float* __restrict__ bv, float* __restrict__ bqkv,
          const float* __restrict__ Wq, const float* __restrict__ Wk,
          const float* __restrict__ Wv, const float* __restrict__ Wo,
          const float* __restrict__ gruk, const float* __restrict__ Wd,
          unsigned short* __restrict__ wqkvT, unsigned short* __restrict__ woT,
          unsigned short* __restrict__ gkT, unsigned short* __restrict__ wdT,
          unsigned int* __restrict__ hbufz, unsigned int* __restrict__ Z)
{
    __shared__ float tile[32][33];
    const int bid = blockIdx.x, tid = threadIdx.x;
    if (bid < 4096) {
        const int i = (bid * 256 + tid) * 4;
        const float4 v = *(const float4*)(x + i);
        const us4 o = {f2bf(v.x), f2bf(v.y), f2bf(v.z), f2bf(v.w)};
        *(us4*)(xb + i) = o;
    } else if (bid < 4102) {
        const int i = (bid - 4096) * 256 + tid;
        bqkv[i] = (i < 512) ? bq[i] : ((i < 1024) ? bk[i - 512] : bv[i - 1024]);
    } else if (bid < 6150) {
        int t = bid - 4102;
        const float* in; unsigned short* out; int N;
        if      (t < 256)  { in = Wq;   out = wqkvT;               N = 512;  }
        else if (t < 512)  { in = Wk;   out = wqkvT + 256 * 1024;  N = 512;  t -= 256;  }
        else if (t < 768)  { in = Wv;   out = wqkvT + 512 * 1024;  N = 512;  t -= 512;  }
        else if (t < 1024) { in = Wo;   out = woT;                 N = 512;  t -= 768;  }
        else if (t < 1792) { in = gruk; out = gkT;                 N = 1536; t -= 1024; }
        else               { in = Wd;   out = wdT;                 N = 512;  t -= 1792; }
        const int tilesx = N / 32;
        const int n0 = (t % tilesx) * 32, k0 = (t / tilesx) * 32;
        const int c = tid & 31, r8 = tid >> 5;
#pragma unroll
        for (int i = 0; i < 4; ++i) {
            const int k = r8 + i * 8;
            tile[k][c] = in[(size_t)(k0 + k) * N + n0 + c];
        }
        __syncthreads();
#pragma unroll
        for (int i = 0; i < 4; ++i) {
            const int n = r8 + i * 8;
            out[(size_t)(n0 + n) * 512 + k0 + c] = f2bf(tile[c][n]);
        }
    } else if (bid == 6150) {
        for (int i = tid; i < 8192; i += 256) hbufz[i] = 0u;
    } else {
        for (int i = tid; i < 2048; i += 256) Z[i] = 0u;
    }
}

// ---------------- bf16 MFMA GEMM: C=A@Bt (+bias)(+resid); f32 C and/or bf16 Cb outputs --------
__global__ __launch_bounds__(256)
void gemm_bf16(const unsigned short* __restrict__ A, const unsigned short* __restrict__ Bt,
               const float* __restrict__ bias, const float* __restrict__ resid,
               float* __restrict__ C, unsigned short* __restrict__ Cb,
               int M, int N, int K)
{
    __shared__ unsigned short As[128 * 64];
    __shared__ unsigned short Bs[128 * 64];
    const int tid = threadIdx.x;
    const int wave = tid >> 6, lane = tid & 63;
    const int bm = blockIdx.x * 128, bn = blockIdx.y * 128;
    const int wr = wave >> 1, wc = wave & 1;
    const int stR = lane >> 3;
    const int stC = (lane & 7) * 8;

    const unsigned short* Abase = A + (size_t)(bm + wave * 32 + stR) * K + stC;
    const unsigned short* Bbase = Bt + (size_t)(bn + wave * 32 + stR) * K + stC;
    unsigned short* AsW = As + wave * 2048;
    unsigned short* BsW = Bs + wave * 2048;

    f32x4 acc[4][4] = {};
    const int fr = lane & 15;
    const int fko = (lane >> 4) * 8;

    for (int k0 = 0; k0 < K; k0 += 64) {
#pragma unroll
        for (int i = 0; i < 4; ++i) {
            gload_lds16(Abase + (size_t)i * 8 * K + k0, AsW + i * 512);
            gload_lds16(Bbase + (size_t)i * 8 * K + k0, BsW + i * 512);
        }
        __syncthreads();
        bf16x8 af[4][2], bfr[4][2];
#pragma unroll
        for (int m = 0; m < 4; ++m) {
            const unsigned short* ap = As + (wr * 64 + m * 16 + fr) * 64 + fko;
            af[m][0] = *(const bf16x8*)(ap);
            af[m][1] = *(const bf16x8*)(ap + 32);
        }
#pragma unroll
        for (int n = 0; n < 4; ++n) {
            const unsigned short* bp = Bs + (wc * 64 + n * 16 + fr) * 64 + fko;
            bfr[n][0] = *(const bf16x8*)(bp);
            bfr[n][1] = *(const bf16x8*)(bp + 32);
        }
#pragma unroll
        for (int m = 0; m < 4; ++m)
#pragma unroll
            for (int n = 0; n < 4; ++n) {
                acc[m][n] = __builtin_amdgcn_mfma_f32_16x16x32_bf16(af[m][0], bfr[n][0], acc[m][n], 0, 0, 0);
                acc[m][n] = __builtin_amdgcn_mfma_f32_16x16x32_bf16(af[m][1], bfr[n][1], acc[m][n], 0, 0, 0);
            }
        __syncthreads();
    }
    const int fq = lane >> 4;
#pragma unroll
    for (int n = 0; n < 4; ++n) {
        const int col = bn + wc * 64 + n * 16 + fr;
        const float bv = bias ? bias[col] : 0.f;
#pragma unroll
        for (int m = 0; m < 4; ++m) {
#pragma unroll
            for (int j = 0; j < 4; ++j) {
                const int row = bm + wr * 64 + m * 16 + fq * 4 + j;
                float v = acc[m][n][j] + bv;
                if (resid) v += resid[(size_t)row * N + col];
                if (C)  C[(size_t)row * N + col] = v;
                if (Cb) Cb[(size_t)row * N + col] = f2bf(v);
            }
        }
    }
}

// ---------------- MFMA attention (r13 proven): 32 q-rows/block, 2 waves -----------------------
__global__ __launch_bounds__(128)
void attn_mfma(const unsigned short* __restrict__ qkv, unsigned short* __restrict__ ctxb)
{
    __shared__ unsigned short P[32][520];
    __shared__ unsigned short KV[64][72];
    __shared__ float invs[32];
    const int tid = threadIdx.x;
    const int wg = blockIdx.x;
    const int qt = wg & 15, h = (wg >> 4) & 7, b = wg >> 7;
    const int t0 = qt * 32;
    const int w = tid >> 6, lane = tid & 63;
    const int lo16 = lane & 15, hi4 = lane >> 4;

    bf16x8 Aq0, Aq1;
    {
        const unsigned short* qrow =
            qkv + ((size_t)(b * 512 + t0 + w * 16 + lo16)) * 1536 + h * 64 + hi4 * 8;
        Aq0 = *(const bf16x8*)(qrow);
        Aq1 = *(const bf16x8*)(qrow + 32);
    }
    const int ss = tid >> 1, sh = tid & 1;

    for (int st = 0; st < 8; ++st) {
        {
            const unsigned short* krow =
                qkv + ((size_t)(b * 512 + st * 64 + ss)) * 1536 + 512 + h * 64 + sh * 32;
            *(bf16x8*)&KV[ss][sh * 32]      = *(const bf16x8*)(krow);
            *(bf16x8*)&KV[ss][sh * 32 + 8]  = *(const bf16x8*)(krow + 8);
            *(bf16x8*)&KV[ss][sh * 32 + 16] = *(const bf16x8*)(krow + 16);
            *(bf16x8*)&KV[ss][sh * 32 + 24] = *(const bf16x8*)(krow + 24);
        }
        __syncthreads();
#pragma unroll
        for (int n = 0; n < 4; ++n) {
            const bf16x8 b0 = *(const bf16x8*)&KV[n * 16 + lo16][hi4 * 8];
            const bf16x8 b1 = *(const bf16x8*)&KV[n * 16 + lo16][32 + hi4 * 8];
            f32x4 acc = {0.f, 0.f, 0.f, 0.f};
            acc = __builtin_amdgcn_mfma_f32_16x16x32_bf16(Aq0, b0, acc, 0, 0, 0);
            acc = __builtin_amdgcn_mfma_f32_16x16x32_bf16(Aq1, b1, acc, 0, 0, 0);
#pragma unroll
            for (int j = 0; j < 4; ++j)
                P[w * 16 + hi4 * 4 + j][st * 64 + n * 16 + lo16] = f2bf(acc[j]);
        }
        __syncthreads();
    }
    {
        const int r = tid >> 2, quad = tid & 3;
        const int c0 = quad * 128;
        float mx = -1e30f;
#pragma unroll
        for (int c8 = 0; c8 < 16; ++c8) {
            const bf16x8 sv = *(const bf16x8*)&P[r][c0 + c8 * 8];
#pragma unroll
            for (int e = 0; e < 8; ++e) mx = fmaxf(mx, bfbits2f((unsigned short)sv[e]));
        }
        mx = fmaxf(mx, __shfl_xor(mx, 1));
        mx = fmaxf(mx, __shfl_xor(mx, 2));
        mx *= 0.125f;
        float sum = 0.f;
#pragma unroll
        for (int c8 = 0; c8 < 16; ++c8) {
            const bf16x8 sv = *(const bf16x8*)&P[r][c0 + c8 * 8];
            us4 o1, o2;
#pragma unroll
            for (int e = 0; e < 8; ++e) {
                const float p = __expf(bfbits2f((unsigned short)sv[e]) * 0.125f - mx);
                sum += p;
                if (e < 4) o1[e] = f2bf(p); else o2[e - 4] = f2bf(p);
            }
            *(us4*)&P[r][c0 + c8 * 8] = o1;
            *(us4*)&P[r][c0 + c8 * 8 + 4] = o2;
        }
        sum += __shfl_xor(sum, 1);
        sum += __shfl_xor(sum, 2);
        if (quad == 0) invs[r] = 1.0f / sum;
    }
    __syncthreads();
    f32x4 oac[4] = {};
    for (int st = 0; st < 8; ++st) {
        {
            const unsigned short* vrow =
                qkv + ((size_t)(b * 512 + st * 64 + ss)) * 1536 + 1024 + h * 64 + sh * 32;
            const bf16x8 v0 = *(const bf16x8*)(vrow);
            const bf16x8 v1 = *(const bf16x8*)(vrow + 8);
            const bf16x8 v2 = *(const bf16x8*)(vrow + 16);
            const bf16x8 v3 = *(const bf16x8*)(vrow + 24);
#pragma unroll
            for (int e = 0; e < 8; ++e) {
                KV[sh * 32 + e][ss]      = (unsigned short)v0[e];
                KV[sh * 32 + 8 + e][ss]  = (unsigned short)v1[e];
                KV[sh * 32 + 16 + e][ss] = (unsigned short)v2[e];
                KV[sh * 32 + 24 + e][ss] = (unsigned short)v3[e];
            }
        }
        __syncthreads();
        const bf16x8 pa0 = *(const bf16x8*)&P[w * 16 + lo16][st * 64 + hi4 * 8];
        const bf16x8 pa1 = *(const bf16x8*)&P[w * 16 + lo16][st * 64 + 32 + hi4 * 8];
#pragma unroll
        for (int n = 0; n < 4; ++n) {
            const bf16x8 b0 = *(const bf16x8*)&KV[n * 16 + lo16][hi4 * 8];
            const bf16x8 b1 = *(const bf16x8*)&KV[n * 16 + lo16][32 + hi4 * 8];
            oac[n] = __builtin_amdgcn_mfma_f32_16x16x32_bf16(pa0, b0, oac[n], 0, 0, 0);
            oac[n] = __builtin_amdgcn_mfma_f32_16x16x32_bf16(pa1, b1, oac[n], 0, 0, 0);
        }
        __syncthreads();
    }
#pragma unroll
    for (int n = 0; n < 4; ++n) {
#pragma unroll
        for (int j = 0; j < 4; ++j) {
            const int q = w * 16 + hi4 * 4 + j;
            ctxb[((size_t)(b * 512 + t0 + q)) * 512 + h * 64 + n * 16 + lo16] =
                f2bf(oac[n][j] * invs[q]);
        }
    }
}

// ---------------- layernorm (rows of 512), optional bf16 side output --------------------------
__global__ __launch_bounds__(256)
void ln_f32(const float* __restrict__ in, float* __restrict__ out,
            const float* __restrict__ g, const float* __restrict__ bb,
            unsigned short* __restrict__ outb)
{
    const int lane = threadIdx.x & 63;
    const int row = blockIdx.x * 4 + (threadIdx.x >> 6);
    const float* x = in + (size_t)row * 512;
    const float4 a = *(const float4*)(x + lane * 4);
    const float4 c = *(const float4*)(x + 256 + lane * 4);
    float s = a.x + a.y + a.z + a.w + c.x + c.y + c.z + c.w;
#pragma unroll
    for (int off = 1; off < 64; off <<= 1) s += __shfl_xor(s, off);
    const float mu = s * (1.0f / 512.0f);
    float vs = 0.f;
    vs += (a.x - mu) * (a.x - mu) + (a.y - mu) * (a.y - mu);
    vs += (a.z - mu) * (a.z - mu) + (a.w - mu) * (a.w - mu);
    vs += (c.x - mu) * (c.x - mu) + (c.y - mu) * (c.y - mu);
    vs += (c.z - mu) * (c.z - mu) + (c.w - mu) * (c.w - mu);
#pragma unroll
    for (int off = 1; off < 64; off <<= 1) vs += __shfl_xor(vs, off);
    const float rstd = rsqrtf(vs * (1.0f / 512.0f) + 1e-3f);
    const float4 g1 = *(const float4*)(g + lane * 4);
    const float4 g2 = *(const float4*)(g + 256 + lane * 4);
    const float4 b1 = *(const float4*)(bb + lane * 4);
    const float4 b2 = *(const float4*)(bb + 256 + lane * 4);
    float* y = out + (size_t)row * 512;
    const float4 o1 = {(a.x - mu) * rstd * g1.x + b1.x, (a.y - mu) * rstd * g1.y + b1.y,
                       (a.z - mu) * rstd * g1.z + b1.z, (a.w - mu) * rstd * g1.w + b1.w};
    const float4 o2 = {(c.x - mu) * rstd * g2.x + b2.x, (c.y - mu) * rstd * g2.y + b2.y,
                       (c.z - mu) * rstd * g2.z + b2.z, (c.w - mu) * rstd * g2.w + b2.w};
    *(float4*)(y + lane * 4) = o1;
    *(float4*)(y + 256 + lane * 4) = o2;
    if (outb) {
        unsigned short* yb = outb + (size_t)row * 512;
        const us4 p1 = {f2bf(o1.x), f2bf(o1.y), f2bf(o1.z), f2bf(o1.w)};
        const us4 p2 = {f2bf(o2.x), f2bf(o2.y), f2bf(o2.z), f2bf(o2.w)};
        *(us4*)(yb + lane * 4) = p1;
        *(us4*)(yb + 256 + lane * 4) = p2;
    }
}

// ---------------- persistent GRU, XCD-pinned: 4 WGs x 8 waves on ONE XCD ---------------------
// r14 change vs r10/r13 (code otherwise identical): 32 column-owner waves packed into 4 WGs of
// 512 threads (220 VGPR -> exactly 8 waves/CU). Halves barrier arrivals (8->4) and pollers,
// skew across 4 CUs instead of 8. Election: launch 64 WGs, rank<4 on argmax XCD participate.
__global__ __launch_bounds__(512, 1)
void gru_persist(const float* __restrict__ rk,
                 const unsigned short* __restrict__ xpb,
                 const float* __restrict__ rb,
                 unsigned short* __restrict__ hbuf,
                 unsigned short* __restrict__ goutb,
                 unsigned int* __restrict__ bar,
                 unsigned int* __restrict__ ctl)
{
    __shared__ int sh_part, sh_memb;
    const int tid = threadIdx.x;

    if (tid == 0) {
        unsigned int xcc;
        asm("s_getreg_b32 %0, hwreg(HW_REG_XCC_ID)" : "=s"(xcc));
        xcc &= 7u;
        const unsigned int rank =
            __hip_atomic_fetch_add(&ctl[xcc], 1u, __ATOMIC_RELAXED, __HIP_MEMORY_SCOPE_AGENT);
        __hip_atomic_fetch_add(&ctl[8], 1u, __ATOMIC_ACQ_REL, __HIP_MEMORY_SCOPE_AGENT);
        unsigned int spins = 0;
        while (__hip_atomic_load(&ctl[8], __ATOMIC_ACQUIRE, __HIP_MEMORY_SCOPE_AGENT)
               < (unsigned)GRID_WGS) {
            __builtin_amdgcn_s_sleep(1);
            if (++spins > (1u << 20)) break;
        }
        unsigned int cnt[8];
#pragma unroll
        for (int i = 0; i < 8; ++i)
            cnt[i] = __hip_atomic_load(&ctl[i], __ATOMIC_ACQUIRE, __HIP_MEMORY_SCOPE_AGENT);
        int best = 0;
#pragma unroll
        for (int i = 1; i < 8; ++i)
            if (cnt[i] > cnt[best]) best = i;
        sh_part = (xcc == (unsigned)best && rank < 4u) ? 1 : 0;
        sh_memb = (int)rank;
    }
    __syncthreads();
    if (!sh_part) return;
    const int member = sh_memb;          // 0..3

    const int wv = tid >> 6, l = tid & 63;
    const int wgi = member * 8 + wv;     // global wave index 0..31
    const int lo16 = l & 15;
    const int hi4 = l >> 4;
    const int gc = wgi * 16 + lo16;

    bf16x8 B[3][16];
#pragma unroll
    for (int g = 0; g < 3; ++g)
#pragma unroll
        for (int kt = 0; kt < 16; ++kt) {
            bf16x8 bv;
#pragma unroll
            for (int j = 0; j < 8; ++j) {
                const int k = kt * 32 + hi4 * 8 + j;
                bv[j] = (short)f2bf(rk[(size_t)k * 1536 + g * 512 + gc]);
            }
            B[g][kt] = bv;
        }
    const float rbz = rb[gc], rbr = rb[512 + gc], rbh = rb[1024 + gc];
    float hst[4] = {0.f, 0.f, 0.f, 0.f};

    float xz[4], xr[4], xh[4];
#pragma unroll
    for (int j = 0; j < 4; ++j) {
        const unsigned short* xrow = xpb + ((size_t)((hi4 * 4 + j) * 512)) * 1536 + gc;
        xz[j] = bfbits2f(xrow[0]); xr[j] = bfbits2f(xrow[512]); xh[j] = bfbits2f(xrow[1024]);
    }
    unsigned int hnb[4] = {0u, 0u, 0u, 0u};

    const unsigned short* ab0 = hbuf + lo16 * 512 + hi4 * 8;
    const unsigned short* ab1 = ab0 + 16 * 512;

    for (int t = 0; t < 512; ++t) {
        const unsigned short* abase = (t & 1) ? ab1 : ab0;
        unsigned short* hw = hbuf + (size_t)((t + 1) & 1) * (16 * 512);
        bf16x8 A[16];
        asm volatile(
            "global_load_dwordx4 %0,  %16, off sc0\n\t"
            "global_load_dwordx4 %1,  %16, off offset:64 sc0\n\t"
            "global_load_dwordx4 %2,  %16, off offset:128 sc0\n\t"
            "global_load_dwordx4 %3,  %16, off offset:192 sc0\n\t"
            "global_load_dwordx4 %4,  %16, off offset:256 sc0\n\t"
            "global_load_dwordx4 %5,  %16, off offset:320 sc0\n\t"
            "global_load_dwordx4 %6,  %16, off offset:384 sc0\n\t"
            "global_load_dwordx4 %7,  %16, off offset:448 sc0\n\t"
            "global_load_dwordx4 %8,  %16, off offset:512 sc0\n\t"
            "global_load_dwordx4 %9,  %16, off offset:576 sc0\n\t"
            "global_load_dwordx4 %10, %16, off offset:640 sc0\n\t"
            "global_load_dwordx4 %11, %16, off offset:704 sc0\n\t"
            "global_load_dwordx4 %12, %16, off offset:768 sc0\n\t"
            "global_load_dwordx4 %13, %16, off offset:832 sc0\n\t"
            "global_load_dwordx4 %14, %16, off offset:896 sc0\n\t"
            "global_load_dwordx4 %15, %16, off offset:960 sc0"
            : "=&v"(A[0]), "=&v"(A[1]), "=&v"(A[2]), "=&v"(A[3]),
              "=&v"(A[4]), "=&v"(A[5]), "=&v"(A[6]), "=&v"(A[7]),
              "=&v"(A[8]), "=&v"(A[9]), "=&v"(A[10]), "=&v"(A[11]),
              "=&v"(A[12]), "=&v"(A[13]), "=&v"(A[14]), "=&v"(A[15])
            : "v"(abase) : "memory");
        unsigned int xnz[4], xnr[4], xnh[4];
        {
            const unsigned short* x0 = xpb + ((size_t)((hi4 * 4 + 0) * 512 + t + 1)) * 1536 + gc;
            const unsigned short* x1 = xpb + ((size_t)((hi4 * 4 + 1) * 512 + t + 1)) * 1536 + gc;
            const unsigned short* x2 = xpb + ((size_t)((hi4 * 4 + 2) * 512 + t + 1)) * 1536 + gc;
            const unsigned short* x3 = xpb + ((size_t)((hi4 * 4 + 3) * 512 + t + 1)) * 1536 + gc;
            asm volatile(
                "global_load_ushort %0,  %12, off\n\t"
                "global_load_ushort %1,  %12, off offset:1024\n\t"
                "global_load_ushort %2,  %12, off offset:2048\n\t"
                "global_load_ushort %3,  %13, off\n\t"
                "global_load_ushort %4,  %13, off offset:1024\n\t"
                "global_load_ushort %5,  %13, off offset:2048\n\t"
                "global_load_ushort %6,  %14, off\n\t"
                "global_load_ushort %7,  %14, off offset:1024\n\t"
                "global_load_ushort %8,  %14, off offset:2048\n\t"
                "global_load_ushort %9,  %15, off\n\t"
                "global_load_ushort %10, %15, off offset:1024\n\t"
                "global_load_ushort %11, %15, off offset:2048"
                : "=&v"(xnz[0]), "=&v"(xnr[0]), "=&v"(xnh[0]),
                  "=&v"(xnz[1]), "=&v"(xnr[1]), "=&v"(xnh[1]),
                  "=&v"(xnz[2]), "=&v"(xnr[2]), "=&v"(xnh[2]),
                  "=&v"(xnz[3]), "=&v"(xnr[3]), "=&v"(xnh[3])
                : "v"(x0), "v"(x1), "v"(x2), "v"(x3) : "memory");
        }
        {
            const int grow = t ? t - 1 : 0;
            unsigned short* g0 = goutb + ((size_t)((hi4 * 4 + 0) * 512 + grow)) * 512 + gc;
            unsigned short* g1 = goutb + ((size_t)((hi4 * 4 + 1) * 512 + grow)) * 512 + gc;
            unsigned short* g2 = goutb + ((size_t)((hi4 * 4 + 2) * 512 + grow)) * 512 + gc;
            unsigned short* g3 = goutb + ((size_t)((hi4 * 4 + 3) * 512 + grow)) * 512 + gc;
            asm volatile(
                "global_store_short %0, %4, off\n\t"
                "global_store_short %1, %5, off\n\t"
                "global_store_short %2, %6, off\n\t"
                "global_store_short %3, %7, off"
                :: "v"(g0), "v"(g1), "v"(g2), "v"(g3),
                   "v"(hnb[0]), "v"(hnb[1]), "v"(hnb[2]), "v"(hnb[3]) : "memory");
        }
        asm volatile("s_waitcnt vmcnt(16)" ::: "memory");
        __builtin_amdgcn_sched_barrier(0);

        f32x4 accz = {0.f, 0.f, 0.f, 0.f};
        f32x4 accr = {0.f, 0.f, 0.f, 0.f};
        f32x4 acch = {0.f, 0.f, 0.f, 0.f};
#pragma unroll
        for (int kt = 0; kt < 16; ++kt) {
            accz = __builtin_amdgcn_mfma_f32_16x16x32_bf16(A[kt], B[0][kt], accz, 0, 0, 0);
            accr = __builtin_amdgcn_mfma_f32_16x16x32_bf16(A[kt], B[1][kt], accr, 0, 0, 0);
            acch = __builtin_amdgcn_mfma_f32_16x16x32_bf16(A[kt], B[2][kt], acch, 0, 0, 0);
        }
#pragma unroll
        for (int j = 0; j < 4; ++j) {
            const int b = hi4 * 4 + j;
            const float z = sigmoidf_(xz[j] + accz[j] + rbz);
            const float r = sigmoidf_(xr[j] + accr[j] + rbr);
            const float hh = fmaxf(xh[j] + r * (acch[j] + rbh), 0.f);
            const float hnew = z * hst[j] + (1.f - z) * hh;
            hst[j] = hnew;
            const unsigned short hb = f2bf(hnew);
            hnb[j] = (unsigned int)hb;
            hw[b * 512 + gc] = hb;
        }
        asm volatile("s_waitcnt vmcnt(0)" ::: "memory");
        __builtin_amdgcn_sched_barrier(0);
#pragma unroll
        for (int j = 0; j < 4; ++j) {
            xz[j] = bfbits2f(xnz[j]); xr[j] = bfbits2f(xnr[j]); xh[j] = bfbits2f(xnh[j]);
        }
        if (t < 511) {
            __syncthreads();
            if (tid == 0) {
                __hip_atomic_fetch_add(bar, 1u, __ATOMIC_RELAXED, __HIP_MEMORY_SCOPE_AGENT);
                const unsigned int target = 4u * (unsigned int)(t + 1);
                unsigned int it = 0;
                while (__hip_atomic_load(bar, __ATOMIC_RELAXED, __HIP_MEMORY_SCOPE_AGENT)
                       < target) {
                    if (++it > (1u << 14)) break;
                }
                if (it > (1u << 14)) {
                    unsigned int cur = 0, it2 = 0;
                    do {
                        asm volatile("global_atomic_add %0, %1, %2, off sc0\n\t"
                                     "s_waitcnt vmcnt(0)"
                                     : "=v"(cur) : "v"(bar), "v"(0u) : "memory");
                        if (++it2 > (1u << 15)) break;
                    } while (cur < target);
                }
            }
            __syncthreads();
        }
    }
#pragma unroll
    for (int j = 0; j < 4; ++j)
        goutb[((size_t)((hi4 * 4 + j) * 512 + 511)) * 512 + gc] = (unsigned short)hnb[j];
}

extern "C" void kernel_launch(void* const* d_in, const int* in_sizes, int n_in,
                              void* d_out, int out_size, void* d_ws, size_t ws_size,
                              hipStream_t stream)
{
    const float* x     = (const float*)d_in[0];
    const float* Wq    = (const float*)d_in[1];
    const float* bq    = (const float*)d_in[2];
    const float* Wk    = (const float*)d_in[3];
    const float* bk    = (const float*)d_in[4];
    const float* Wv    = (const float*)d_in[5];
    const float* bv    = (const float*)d_in[6];
    const float* Wo    = (const float*)d_in[7];
    const float* bo    = (const float*)d_in[8];
    const float* ln1g  = (const float*)d_in[9];
    const float* ln1b  = (const float*)d_in[10];
    const float* gruk  = (const float*)d_in[11];
    const float* grurk = (const float*)d_in[12];
    const float* grub  = (const float*)d_in[13];
    const float* Wd    = (const float*)d_in[14];
    const float* bd    = (const float*)d_in[15];
    const float* ln2g  = (const float*)d_in[16];
    const float* ln2b  = (const float*)d_in[17];
    float* out = (float*)d_out;

    char* base = (char*)d_ws;
    const size_t MB = 1024 * 1024;
    unsigned short* qkvb = (unsigned short*)base;
    unsigned short* xpb  = (unsigned short*)base;
    float*          dout = (float*)(base + 24 * MB);
    float*          R4   = (float*)(base + 48 * MB);
    unsigned short* S1   = (unsigned short*)(base + 64 * MB);
    unsigned short* WT   = (unsigned short*)(base + 72 * MB);
    unsigned short* wqkvT = WT;
    unsigned short* woT  = WT + 768 * 1024;
    unsigned short* gkT  = WT + 1024 * 1024;
    unsigned short* wdT  = WT + 1792 * 1024;
    unsigned short* hbuf = (unsigned short*)(base + 76 * MB);
    char*           Z    = base + 76 * MB + 64 * 1024;
    unsigned int*   ctl  = (unsigned int*)(Z);
    unsigned int*   bar  = (unsigned int*)(Z + 256);
    float*          bqkv = (float*)(base + 77 * MB);

    const dim3 blk(256);
    const dim3 g512(8192 / 128, 512 / 128);
    const dim3 g1536(8192 / 128, 1536 / 128);

    prep<<<dim3(6152), blk, 0, stream>>>(x, S1, bq, bk, bv, bqkv,
                                         Wq, Wk, Wv, Wo, gruk, Wd,
                                         wqkvT, woT, gkT, wdT,
                                         (unsigned int*)hbuf, (unsigned int*)Z);
    gemm_bf16<<<g1536, blk, 0, stream>>>(S1, wqkvT, bqkv, nullptr, nullptr, qkvb, 8192, 1536, 512);
    attn_mfma<<<dim3(2048), dim3(128), 0, stream>>>(qkvb, S1);
    gemm_bf16<<<g512, blk, 0, stream>>>(S1, woT, bo, x, R4, nullptr, 8192, 512, 512);
    ln_f32<<<dim3(2048), blk, 0, stream>>>(R4, R4, ln1g, ln1b, S1);
    gemm_bf16<<<g1536, blk, 0, stream>>>(S1, gkT, grub, nullptr, nullptr, xpb, 8192, 1536, 512);
    gru_persist<<<dim3(GRID_WGS), dim3(512), 0, stream>>>(grurk, xpb, grub + 1536, hbuf, S1, bar, ctl);
    gemm_bf16<<<g512, blk, 0, stream>>>(S1, wdT, bd, R4, dout, nullptr, 8192, 512, 512);
    ln_f32<<<dim3(2048), blk, 0, stream>>>(dout, out, ln2g, ln2b, nullptr);
}

// Round 15
// 4735.199 us; speedup vs baseline: 1.0275x; 1.0275x over previous
//
#include <hip/hip_runtime.h>
#include <math.h>

// B=16, T=512, F=512, H=8, D=64; rows = B*T = 8192
#define GRID_WGS 64   // launched WGs for GRU (512 thr each); 4 elected (same XCD) participate

typedef __attribute__((ext_vector_type(8))) short bf16x8;
typedef __attribute__((ext_vector_type(4))) float f32x4;
typedef __attribute__((ext_vector_type(4))) unsigned short us4;

static __device__ __forceinline__ float sigmoidf_(float x) {
    return 1.0f / (1.0f + __expf(-x));
}
static __device__ __forceinline__ unsigned short f2bf(float f) {
    unsigned int u = __float_as_uint(f);
    u += 0x7fffu + ((u >> 16) & 1u);
    return (unsigned short)(u >> 16);
}
static __device__ __forceinline__ float bfbits2f(unsigned int b) {
    return __uint_as_float(b << 16);
}
static __device__ __forceinline__ void gload_lds16(const void* g, void* l) {
    __builtin_amdgcn_global_load_lds(
        (const __attribute__((address_space(1))) unsigned int*)g,
        (__attribute__((address_space(3))) unsigned int*)l, 16, 0, 0);
}

// ---------------- prep: f2bf(x) + bias concat + 6 weight transposes + zero hbuf/Z -------------
__global__ __launch_bounds__(256)
void prep(const float* __restrict__ x, unsigned short* __restrict__ xb,
          const float* __restrict__ bq, const float* __restrict__ bk,
          const float* __restrict__ bv, float* __restrict__ bqkv,
          const float* __restrict__ Wq, const float* __restrict__ Wk,
          const float* __restrict__ Wv, const float* __restrict__ Wo,
          const float* __restrict__ gruk, const float* __restrict__ Wd,
          unsigned short* __restrict__ wqkvT, unsigned short* __restrict__ woT,
          unsigned short* __restrict__ gkT, unsigned short* __restrict__ wdT,
          unsigned int* __restrict__ hbufz, unsigned int* __restrict__ Z)
{
    __shared__ float tile[32][33];
    const int bid = blockIdx.x, tid = threadIdx.x;
    if (bid < 4096) {
        const int i = (bid * 256 + tid) * 4;
        const float4 v = *(const float4*)(x + i);
        const us4 o = {f2bf(v.x), f2bf(v.y), f2bf(v.z), f2bf(v.w)};
        *(us4*)(xb + i) = o;
    } else if (bid < 4102) {
        const int i = (bid - 4096) * 256 + tid;
        bqkv[i] = (i < 512) ? bq[i] : ((i < 1024) ? bk[i - 512] : bv[i - 1024]);
    } else if (bid < 6150) {
        int t = bid - 4102;
        const float* in; unsigned short* out; int N;
        if      (t < 256)  { in = Wq;   out = wqkvT;               N = 512;  }
        else if (t < 512)  { in = Wk;   out = wqkvT + 256 * 1024;  N = 512;  t -= 256;  }
        else if (t < 768)  { in = Wv;   out = wqkvT + 512 * 1024;  N = 512;  t -= 512;  }
        else if (t < 1024) { in = Wo;   out = woT;                 N = 512;  t -= 768;  }
        else if (t < 1792) { in = gruk; out = gkT;                 N = 1536; t -= 1024; }
        else               { in = Wd;   out = wdT;                 N = 512;  t -= 1792; }
        const int tilesx = N / 32;
        const int n0 = (t % tilesx) * 32, k0 = (t / tilesx) * 32;
        const int c = tid & 31, r8 = tid >> 5;
#pragma unroll
        for (int i = 0; i < 4; ++i) {
            const int k = r8 + i * 8;
            tile[k][c] = in[(size_t)(k0 + k) * N + n0 + c];
        }
        __syncthreads();
#pragma unroll
        for (int i = 0; i < 4; ++i) {
            const int n = r8 + i * 8;
            out[(size_t)(n0 + n) * 512 + k0 + c] = f2bf(tile[c][n]);
        }
    } else if (bid == 6150) {
        for (int i = tid; i < 8192; i += 256) hbufz[i] = 0u;
    } else {
        for (int i = tid; i < 2048; i += 256) Z[i] = 0u;
    }
}

// ---------------- bf16 MFMA GEMM: C=A@Bt (+bias)(+resid); f32 C and/or bf16 Cb outputs --------
__global__ __launch_bounds__(256)
void gemm_bf16(const unsigned short* __restrict__ A, const unsigned short* __restrict__ Bt,
               const float* __restrict__ bias, const float* __restrict__ resid,
               float* __restrict__ C, unsigned short* __restrict__ Cb,
               int M, int N, int K)
{
    __shared__ unsigned short As[128 * 64];
    __shared__ unsigned short Bs[128 * 64];
    const int tid = threadIdx.x;
    const int wave = tid >> 6, lane = tid & 63;
    const int bm = blockIdx.x * 128, bn = blockIdx.y * 128;
    const int wr = wave >> 1, wc = wave & 1;
    const int stR = lane >> 3;
    const int stC = (lane & 7) * 8;

    const unsigned short* Abase = A + (size_t)(bm + wave * 32 + stR) * K + stC;
    const unsigned short* Bbase = Bt + (size_t)(bn + wave * 32 + stR) * K + stC;
    unsigned short* AsW = As + wave * 2048;
    unsigned short* BsW = Bs + wave * 2048;

    f32x4 acc[4][4] = {};
    const int fr = lane & 15;
    const int fko = (lane >> 4) * 8;

    for (int k0 = 0; k0 < K; k0 += 64) {
#pragma unroll
        for (int i = 0; i < 4; ++i) {
            gload_lds16(Abase + (size_t)i * 8 * K + k0, AsW + i * 512);
            gload_lds16(Bbase + (size_t)i * 8 * K + k0, BsW + i * 512);
        }
        __syncthreads();
        bf16x8 af[4][2], bfr[4][2];
#pragma unroll
        for (int m = 0; m < 4; ++m) {
            const unsigned short* ap = As + (wr * 64 + m * 16 + fr) * 64 + fko;
            af[m][0] = *(const bf16x8*)(ap);
            af[m][1] = *(const bf16x8*)(ap + 32);
        }
#pragma unroll
        for (int n = 0; n < 4; ++n) {
            const unsigned short* bp = Bs + (wc * 64 + n * 16 + fr) * 64 + fko;
            bfr[n][0] = *(const bf16x8*)(bp);
            bfr[n][1] = *(const bf16x8*)(bp + 32);
        }
#pragma unroll
        for (int m = 0; m < 4; ++m)
#pragma unroll
            for (int n = 0; n < 4; ++n) {
                acc[m][n] = __builtin_amdgcn_mfma_f32_16x16x32_bf16(af[m][0], bfr[n][0], acc[m][n], 0, 0, 0);
                acc[m][n] = __builtin_amdgcn_mfma_f32_16x16x32_bf16(af[m][1], bfr[n][1], acc[m][n], 0, 0, 0);
            }
        __syncthreads();
    }
    const int fq = lane >> 4;
#pragma unroll
    for (int n = 0; n < 4; ++n) {
        const int col = bn + wc * 64 + n * 16 + fr;
        const float bv = bias ? bias[col] : 0.f;
#pragma unroll
        for (int m = 0; m < 4; ++m) {
#pragma unroll
            for (int j = 0; j < 4; ++j) {
                const int row = bm + wr * 64 + m * 16 + fq * 4 + j;
                float v = acc[m][n][j] + bv;
                if (resid) v += resid[(size_t)row * N + col];
                if (C)  C[(size_t)row * N + col] = v;
                if (Cb) Cb[(size_t)row * N + col] = f2bf(v);
            }
        }
    }
}

// ---------------- MFMA attention (r13 proven): 32 q-rows/block, 2 waves -----------------------
__global__ __launch_bounds__(128)
void attn_mfma(const unsigned short* __restrict__ qkv, unsigned short* __restrict__ ctxb)
{
    __shared__ unsigned short P[32][520];
    __shared__ unsigned short KV[64][72];
    __shared__ float invs[32];
    const int tid = threadIdx.x;
    const int wg = blockIdx.x;
    const int qt = wg & 15, h = (wg >> 4) & 7, b = wg >> 7;
    const int t0 = qt * 32;
    const int w = tid >> 6, lane = tid & 63;
    const int lo16 = lane & 15, hi4 = lane >> 4;

    bf16x8 Aq0, Aq1;
    {
        const unsigned short* qrow =
            qkv + ((size_t)(b * 512 + t0 + w * 16 + lo16)) * 1536 + h * 64 + hi4 * 8;
        Aq0 = *(const bf16x8*)(qrow);
        Aq1 = *(const bf16x8*)(qrow + 32);
    }
    const int ss = tid >> 1, sh = tid & 1;

    for (int st = 0; st < 8; ++st) {
        {
            const unsigned short* krow =
                qkv + ((size_t)(b * 512 + st * 64 + ss)) * 1536 + 512 + h * 64 + sh * 32;
            *(bf16x8*)&KV[ss][sh * 32]      = *(const bf16x8*)(krow);
            *(bf16x8*)&KV[ss][sh * 32 + 8]  = *(const bf16x8*)(krow + 8);
            *(bf16x8*)&KV[ss][sh * 32 + 16] = *(const bf16x8*)(krow + 16);
            *(bf16x8*)&KV[ss][sh * 32 + 24] = *(const bf16x8*)(krow + 24);
        }
        __syncthreads();
#pragma unroll
        for (int n = 0; n < 4; ++n) {
            const bf16x8 b0 = *(const bf16x8*)&KV[n * 16 + lo16][hi4 * 8];
            const bf16x8 b1 = *(const bf16x8*)&KV[n * 16 + lo16][32 + hi4 * 8];
            f32x4 acc = {0.f, 0.f, 0.f, 0.f};
            acc = __builtin_amdgcn_mfma_f32_16x16x32_bf16(Aq0, b0, acc, 0, 0, 0);
            acc = __builtin_amdgcn_mfma_f32_16x16x32_bf16(Aq1, b1, acc, 0, 0, 0);
#pragma unroll
            for (int j = 0; j < 4; ++j)
                P[w * 16 + hi4 * 4 + j][st * 64 + n * 16 + lo16] = f2bf(acc[j]);
        }
        __syncthreads();
    }
    {
        const int r = tid >> 2, quad = tid & 3;
        const int c0 = quad * 128;
        float mx = -1e30f;
#pragma unroll
        for (int c8 = 0; c8 < 16; ++c8) {
            const bf16x8 sv = *(const bf16x8*)&P[r][c0 + c8 * 8];
#pragma unroll
            for (int e = 0; e < 8; ++e) mx = fmaxf(mx, bfbits2f((unsigned short)sv[e]));
        }
        mx = fmaxf(mx, __shfl_xor(mx, 1));
        mx = fmaxf(mx, __shfl_xor(mx, 2));
        mx *= 0.125f;
        float sum = 0.f;
#pragma unroll
        for (int c8 = 0; c8 < 16; ++c8) {
            const bf16x8 sv = *(const bf16x8*)&P[r][c0 + c8 * 8];
            us4 o1, o2;
#pragma unroll
            for (int e = 0; e < 8; ++e) {
                const float p = __expf(bfbits2f((unsigned short)sv[e]) * 0.125f - mx);
                sum += p;
                if (e < 4) o1[e] = f2bf(p); else o2[e - 4] = f2bf(p);
            }
            *(us4*)&P[r][c0 + c8 * 8] = o1;
            *(us4*)&P[r][c0 + c8 * 8 + 4] = o2;
        }
        sum += __shfl_xor(sum, 1);
        sum += __shfl_xor(sum, 2);
        if (quad == 0) invs[r] = 1.0f / sum;
    }
    __syncthreads();
    f32x4 oac[4] = {};
    for (int st = 0; st < 8; ++st) {
        {
            const unsigned short* vrow =
                qkv + ((size_t)(b * 512 + st * 64 + ss)) * 1536 + 1024 + h * 64 + sh * 32;
            const bf16x8 v0 = *(const bf16x8*)(vrow);
            const bf16x8 v1 = *(const bf16x8*)(vrow + 8);
            const bf16x8 v2 = *(const bf16x8*)(vrow + 16);
            const bf16x8 v3 = *(const bf16x8*)(vrow + 24);
#pragma unroll
            for (int e = 0; e < 8; ++e) {
                KV[sh * 32 + e][ss]      = (unsigned short)v0[e];
                KV[sh * 32 + 8 + e][ss]  = (unsigned short)v1[e];
                KV[sh * 32 + 16 + e][ss] = (unsigned short)v2[e];
                KV[sh * 32 + 24 + e][ss] = (unsigned short)v3[e];
            }
        }
        __syncthreads();
        const bf16x8 pa0 = *(const bf16x8*)&P[w * 16 + lo16][st * 64 + hi4 * 8];
        const bf16x8 pa1 = *(const bf16x8*)&P[w * 16 + lo16][st * 64 + 32 + hi4 * 8];
#pragma unroll
        for (int n = 0; n < 4; ++n) {
            const bf16x8 b0 = *(const bf16x8*)&KV[n * 16 + lo16][hi4 * 8];
            const bf16x8 b1 = *(const bf16x8*)&KV[n * 16 + lo16][32 + hi4 * 8];
            oac[n] = __builtin_amdgcn_mfma_f32_16x16x32_bf16(pa0, b0, oac[n], 0, 0, 0);
            oac[n] = __builtin_amdgcn_mfma_f32_16x16x32_bf16(pa1, b1, oac[n], 0, 0, 0);
        }
        __syncthreads();
    }
#pragma unroll
    for (int n = 0; n < 4; ++n) {
#pragma unroll
        for (int j = 0; j < 4; ++j) {
            const int q = w * 16 + hi4 * 4 + j;
            ctxb[((size_t)(b * 512 + t0 + q)) * 512 + h * 64 + n * 16 + lo16] =
                f2bf(oac[n][j] * invs[q]);
        }
    }
}

// ---------------- layernorm (rows of 512), optional bf16 side output --------------------------
__global__ __launch_bounds__(256)
void ln_f32(const float* __restrict__ in, float* __restrict__ out,
            const float* __restrict__ g, const float* __restrict__ bb,
            unsigned short* __restrict__ outb)
{
    const int lane = threadIdx.x & 63;
    const int row = blockIdx.x * 4 + (threadIdx.x >> 6);
    const float* x = in + (size_t)row * 512;
    const float4 a = *(const float4*)(x + lane * 4);
    const float4 c = *(const float4*)(x + 256 + lane * 4);
    float s = a.x + a.y + a.z + a.w + c.x + c.y + c.z + c.w;
#pragma unroll
    for (int off = 1; off < 64; off <<= 1) s += __shfl_xor(s, off);
    const float mu = s * (1.0f / 512.0f);
    float vs = 0.f;
    vs += (a.x - mu) * (a.x - mu) + (a.y - mu) * (a.y - mu);
    vs += (a.z - mu) * (a.z - mu) + (a.w - mu) * (a.w - mu);
    vs += (c.x - mu) * (c.x - mu) + (c.y - mu) * (c.y - mu);
    vs += (c.z - mu) * (c.z - mu) + (c.w - mu) * (c.w - mu);
#pragma unroll
    for (int off = 1; off < 64; off <<= 1) vs += __shfl_xor(vs, off);
    const float rstd = rsqrtf(vs * (1.0f / 512.0f) + 1e-3f);
    const float4 g1 = *(const float4*)(g + lane * 4);
    const float4 g2 = *(const float4*)(g + 256 + lane * 4);
    const float4 b1 = *(const float4*)(bb + lane * 4);
    const float4 b2 = *(const float4*)(bb + 256 + lane * 4);
    float* y = out + (size_t)row * 512;
    const float4 o1 = {(a.x - mu) * rstd * g1.x + b1.x, (a.y - mu) * rstd * g1.y + b1.y,
                       (a.z - mu) * rstd * g1.z + b1.z, (a.w - mu) * rstd * g1.w + b1.w};
    const float4 o2 = {(c.x - mu) * rstd * g2.x + b2.x, (c.y - mu) * rstd * g2.y + b2.y,
                       (c.z - mu) * rstd * g2.z + b2.z, (c.w - mu) * rstd * g2.w + b2.w};
    *(float4*)(y + lane * 4) = o1;
    *(float4*)(y + 256 + lane * 4) = o2;
    if (outb) {
        unsigned short* yb = outb + (size_t)row * 512;
        const us4 p1 = {f2bf(o1.x), f2bf(o1.y), f2bf(o1.z), f2bf(o1.w)};
        const us4 p2 = {f2bf(o2.x), f2bf(o2.y), f2bf(o2.z), f2bf(o2.w)};
        *(us4*)(yb + lane * 4) = p1;
        *(us4*)(yb + 256 + lane * 4) = p2;
    }
}

// ---------------- persistent GRU, XCD-pinned: 4 WGs x 8 waves on ONE XCD ---------------------
// r15: r14 retried with CORRECT launch spec. __launch_bounds__(512, 2): 2 waves/EU x 4 SIMD
// / 8 waves-per-block = 1 WG/CU, VGPR cap 256 >= 220 needed -> weights stay in registers
// (r14's (512,1) spec was inconsistent and spilled at 128 VGPR). 4 barrier arrivals, 4 pollers.
__global__ __launch_bounds__(512, 2)
void gru_persist(const float* __restrict__ rk,
                 const unsigned short* __restrict__ xpb,
                 const float* __restrict__ rb,
                 unsigned short* __restrict__ hbuf,
                 unsigned short* __restrict__ goutb,
                 unsigned int* __restrict__ bar,
                 unsigned int* __restrict__ ctl)
{
    __shared__ int sh_part, sh_memb;
    const int tid = threadIdx.x;

    if (tid == 0) {
        unsigned int xcc;
        asm("s_getreg_b32 %0, hwreg(HW_REG_XCC_ID)" : "=s"(xcc));
        xcc &= 7u;
        const unsigned int rank =
            __hip_atomic_fetch_add(&ctl[xcc], 1u, __ATOMIC_RELAXED, __HIP_MEMORY_SCOPE_AGENT);
        __hip_atomic_fetch_add(&ctl[8], 1u, __ATOMIC_ACQ_REL, __HIP_MEMORY_SCOPE_AGENT);
        unsigned int spins = 0;
        while (__hip_atomic_load(&ctl[8], __ATOMIC_ACQUIRE, __HIP_MEMORY_SCOPE_AGENT)
               < (unsigned)GRID_WGS) {
            __builtin_amdgcn_s_sleep(1);
            if (++spins > (1u << 20)) break;
        }
        unsigned int cnt[8];
#pragma unroll
        for (int i = 0; i < 8; ++i)
            cnt[i] = __hip_atomic_load(&ctl[i], __ATOMIC_ACQUIRE, __HIP_MEMORY_SCOPE_AGENT);
        int best = 0;
#pragma unroll
        for (int i = 1; i < 8; ++i)
            if (cnt[i] > cnt[best]) best = i;
        sh_part = (xcc == (unsigned)best && rank < 4u) ? 1 : 0;
        sh_memb = (int)rank;
    }
    __syncthreads();
    if (!sh_part) return;
    const int member = sh_memb;          // 0..3

    const int wv = tid >> 6, l = tid & 63;
    const int wgi = member * 8 + wv;     // global wave index 0..31
    const int lo16 = l & 15;
    const int hi4 = l >> 4;
    const int gc = wgi * 16 + lo16;

    bf16x8 B[3][16];
#pragma unroll
    for (int g = 0; g < 3; ++g)
#pragma unroll
        for (int kt = 0; kt < 16; ++kt) {
            bf16x8 bv;
#pragma unroll
            for (int j = 0; j < 8; ++j) {
                const int k = kt * 32 + hi4 * 8 + j;
                bv[j] = (short)f2bf(rk[(size_t)k * 1536 + g * 512 + gc]);
            }
            B[g][kt] = bv;
        }
    const float rbz = rb[gc], rbr = rb[512 + gc], rbh = rb[1024 + gc];
    float hst[4] = {0.f, 0.f, 0.f, 0.f};

    float xz[4], xr[4], xh[4];
#pragma unroll
    for (int j = 0; j < 4; ++j) {
        const unsigned short* xrow = xpb + ((size_t)((hi4 * 4 + j) * 512)) * 1536 + gc;
        xz[j] = bfbits2f(xrow[0]); xr[j] = bfbits2f(xrow[512]); xh[j] = bfbits2f(xrow[1024]);
    }
    unsigned int hnb[4] = {0u, 0u, 0u, 0u};

    const unsigned short* ab0 = hbuf + lo16 * 512 + hi4 * 8;
    const unsigned short* ab1 = ab0 + 16 * 512;

    for (int t = 0; t < 512; ++t) {
        const unsigned short* abase = (t & 1) ? ab1 : ab0;
        unsigned short* hw = hbuf + (size_t)((t + 1) & 1) * (16 * 512);
        bf16x8 A[16];
        asm volatile(
            "global_load_dwordx4 %0,  %16, off sc0\n\t"
            "global_load_dwordx4 %1,  %16, off offset:64 sc0\n\t"
            "global_load_dwordx4 %2,  %16, off offset:128 sc0\n\t"
            "global_load_dwordx4 %3,  %16, off offset:192 sc0\n\t"
            "global_load_dwordx4 %4,  %16, off offset:256 sc0\n\t"
            "global_load_dwordx4 %5,  %16, off offset:320 sc0\n\t"
            "global_load_dwordx4 %6,  %16, off offset:384 sc0\n\t"
            "global_load_dwordx4 %7,  %16, off offset:448 sc0\n\t"
            "global_load_dwordx4 %8,  %16, off offset:512 sc0\n\t"
            "global_load_dwordx4 %9,  %16, off offset:576 sc0\n\t"
            "global_load_dwordx4 %10, %16, off offset:640 sc0\n\t"
            "global_load_dwordx4 %11, %16, off offset:704 sc0\n\t"
            "global_load_dwordx4 %12, %16, off offset:768 sc0\n\t"
            "global_load_dwordx4 %13, %16, off offset:832 sc0\n\t"
            "global_load_dwordx4 %14, %16, off offset:896 sc0\n\t"
            "global_load_dwordx4 %15, %16, off offset:960 sc0"
            : "=&v"(A[0]), "=&v"(A[1]), "=&v"(A[2]), "=&v"(A[3]),
              "=&v"(A[4]), "=&v"(A[5]), "=&v"(A[6]), "=&v"(A[7]),
              "=&v"(A[8]), "=&v"(A[9]), "=&v"(A[10]), "=&v"(A[11]),
              "=&v"(A[12]), "=&v"(A[13]), "=&v"(A[14]), "=&v"(A[15])
            : "v"(abase) : "memory");
        unsigned int xnz[4], xnr[4], xnh[4];
        {
            const unsigned short* x0 = xpb + ((size_t)((hi4 * 4 + 0) * 512 + t + 1)) * 1536 + gc;
            const unsigned short* x1 = xpb + ((size_t)((hi4 * 4 + 1) * 512 + t + 1)) * 1536 + gc;
            const unsigned short* x2 = xpb + ((size_t)((hi4 * 4 + 2) * 512 + t + 1)) * 1536 + gc;
            const unsigned short* x3 = xpb + ((size_t)((hi4 * 4 + 3) * 512 + t + 1)) * 1536 + gc;
            asm volatile(
                "global_load_ushort %0,  %12, off\n\t"
                "global_load_ushort %1,  %12, off offset:1024\n\t"
                "global_load_ushort %2,  %12, off offset:2048\n\t"
                "global_load_ushort %3,  %13, off\n\t"
                "global_load_ushort %4,  %13, off offset:1024\n\t"
                "global_load_ushort %5,  %13, off offset:2048\n\t"
                "global_load_ushort %6,  %14, off\n\t"
                "global_load_ushort %7,  %14, off offset:1024\n\t"
                "global_load_ushort %8,  %14, off offset:2048\n\t"
                "global_load_ushort %9,  %15, off\n\t"
                "global_load_ushort %10, %15, off offset:1024\n\t"
                "global_load_ushort %11, %15, off offset:2048"
                : "=&v"(xnz[0]), "=&v"(xnr[0]), "=&v"(xnh[0]),
                  "=&v"(xnz[1]), "=&v"(xnr[1]), "=&v"(xnh[1]),
                  "=&v"(xnz[2]), "=&v"(xnr[2]), "=&v"(xnh[2]),
                  "=&v"(xnz[3]), "=&v"(xnr[3]), "=&v"(xnh[3])
                : "v"(x0), "v"(x1), "v"(x2), "v"(x3) : "memory");
        }
        {
            const int grow = t ? t - 1 : 0;
            unsigned short* g0 = goutb + ((size_t)((hi4 * 4 + 0) * 512 + grow)) * 512 + gc;
            unsigned short* g1 = goutb + ((size_t)((hi4 * 4 + 1) * 512 + grow)) * 512 + gc;
            unsigned short* g2 = goutb + ((size_t)((hi4 * 4 + 2) * 512 + grow)) * 512 + gc;
            unsigned short* g3 = goutb + ((size_t)((hi4 * 4 + 3) * 512 + grow)) * 512 + gc;
            asm volatile(
                "global_store_short %0, %4, off\n\t"
                "global_store_short %1, %5, off\n\t"
                "global_store_short %2, %6, off\n\t"
                "global_store_short %3, %7, off"
                :: "v"(g0), "v"(g1), "v"(g2), "v"(g3),
                   "v"(hnb[0]), "v"(hnb[1]), "v"(hnb[2]), "v"(hnb[3]) : "memory");
        }
        asm volatile("s_waitcnt vmcnt(16)" ::: "memory");
        __builtin_amdgcn_sched_barrier(0);

        f32x4 accz = {0.f, 0.f, 0.f, 0.f};
        f32x4 accr = {0.f, 0.f, 0.f, 0.f};
        f32x4 acch = {0.f, 0.f, 0.f, 0.f};
#pragma unroll
        for (int kt = 0; kt < 16; ++kt) {
            accz = __builtin_amdgcn_mfma_f32_16x16x32_bf16(A[kt], B[0][kt], accz, 0, 0, 0);
            accr = __builtin_amdgcn_mfma_f32_16x16x32_bf16(A[kt], B[1][kt], accr, 0, 0, 0);
            acch = __builtin_amdgcn_mfma_f32_16x16x32_bf16(A[kt], B[2][kt], acch, 0, 0, 0);
        }
#pragma unroll
        for (int j = 0; j < 4; ++j) {
            const int b = hi4 * 4 + j;
            const float z = sigmoidf_(xz[j] + accz[j] + rbz);
            const float r = sigmoidf_(xr[j] + accr[j] + rbr);
            const float hh = fmaxf(xh[j] + r * (acch[j] + rbh), 0.f);
            const float hnew = z * hst[j] + (1.f - z) * hh;
            hst[j] = hnew;
            const unsigned short hb = f2bf(hnew);
            hnb[j] = (unsigned int)hb;
            hw[b * 512 + gc] = hb;
        }
        asm volatile("s_waitcnt vmcnt(0)" ::: "memory");
        __builtin_amdgcn_sched_barrier(0);
#pragma unroll
        for (int j = 0; j < 4; ++j) {
            xz[j] = bfbits2f(xnz[j]); xr[j] = bfbits2f(xnr[j]); xh[j] = bfbits2f(xnh[j]);
        }
        if (t < 511) {
            __syncthreads();
            if (tid == 0) {
                __hip_atomic_fetch_add(bar, 1u, __ATOMIC_RELAXED, __HIP_MEMORY_SCOPE_AGENT);
                const unsigned int target = 4u * (unsigned int)(t + 1);
                unsigned int it = 0;
                while (__hip_atomic_load(bar, __ATOMIC_RELAXED, __HIP_MEMORY_SCOPE_AGENT)
                       < target) {
                    if (++it > (1u << 14)) break;
                }
                if (it > (1u << 14)) {
                    unsigned int cur = 0, it2 = 0;
                    do {
                        asm volatile("global_atomic_add %0, %1, %2, off sc0\n\t"
                                     "s_waitcnt vmcnt(0)"
                                     : "=v"(cur) : "v"(bar), "v"(0u) : "memory");
                        if (++it2 > (1u << 15)) break;
                    } while (cur < target);
                }
            }
            __syncthreads();
        }
    }
#pragma unroll
    for (int j = 0; j < 4; ++j)
        goutb[((size_t)((hi4 * 4 + j) * 512 + 511)) * 512 + gc] = (unsigned short)hnb[j];
}

extern "C" void kernel_launch(void* const* d_in, const int* in_sizes, int n_in,
                              void* d_out, int out_size, void* d_ws, size_t ws_size,
                              hipStream_t stream)
{
    const float* x     = (const float*)d_in[0];
    const float* Wq    = (const float*)d_in[1];
    const float* bq    = (const float*)d_in[2];
    const float* Wk    = (const float*)d_in[3];
    const float* bk    = (const float*)d_in[4];
    const float* Wv    = (const float*)d_in[5];
    const float* bv    = (const float*)d_in[6];
    const float* Wo    = (const float*)d_in[7];
    const float* bo    = (const float*)d_in[8];
    const float* ln1g  = (const float*)d_in[9];
    const float* ln1b  = (const float*)d_in[10];
    const float* gruk  = (const float*)d_in[11];
    const float* grurk = (const float*)d_in[12];
    const float* grub  = (const float*)d_in[13];
    const float* Wd    = (const float*)d_in[14];
    const float* bd    = (const float*)d_in[15];
    const float* ln2g  = (const float*)d_in[16];
    const float* ln2b  = (const float*)d_in[17];
    float* out = (float*)d_out;

    char* base = (char*)d_ws;
    const size_t MB = 1024 * 1024;
    unsigned short* qkvb = (unsigned short*)base;
    unsigned short* xpb  = (unsigned short*)base;
    float*          dout = (float*)(base + 24 * MB);
    float*          R4   = (float*)(base + 48 * MB);
    unsigned short* S1   = (unsigned short*)(base + 64 * MB);
    unsigned short* WT   = (unsigned short*)(base + 72 * MB);
    unsigned short* wqkvT = WT;
    unsigned short* woT  = WT + 768 * 1024;
    unsigned short* gkT  = WT + 1024 * 1024;
    unsigned short* wdT  = WT + 1792 * 1024;
    unsigned short* hbuf = (unsigned short*)(base + 76 * MB);
    char*           Z    = base + 76 * MB + 64 * 1024;
    unsigned int*   ctl  = (unsigned int*)(Z);
    unsigned int*   bar  = (unsigned int*)(Z + 256);
    float*          bqkv = (float*)(base + 77 * MB);

    const dim3 blk(256);
    const dim3 g512(8192 / 128, 512 / 128);
    const dim3 g1536(8192 / 128, 1536 / 128);

    prep<<<dim3(6152), blk, 0, stream>>>(x, S1, bq, bk, bv, bqkv,
                                         Wq, Wk, Wv, Wo, gruk, Wd,
                                         wqkvT, woT, gkT, wdT,
                                         (unsigned int*)hbuf, (unsigned int*)Z);
    gemm_bf16<<<g1536, blk, 0, stream>>>(S1, wqkvT, bqkv, nullptr, nullptr, qkvb, 8192, 1536, 512);
    attn_mfma<<<dim3(2048), dim3(128), 0, stream>>>(qkvb, S1);
    gemm_bf16<<<g512, blk, 0, stream>>>(S1, woT, bo, x, R4, nullptr, 8192, 512, 512);
    ln_f32<<<dim3(2048), blk, 0, stream>>>(R4, R4, ln1g, ln1b, S1);
    gemm_bf16<<<g1536, blk, 0, stream>>>(S1, gkT, grub, nullptr, nullptr, xpb, 8192, 1536, 512);
    gru_persist<<<dim3(GRID_WGS), dim3(512), 0, stream>>>(grurk, xpb, grub + 1536, hbuf, S1, bar, ctl);
    gemm_bf16<<<g512, blk, 0, stream>>>(S1, wdT, bd, R4, dout, nullptr, 8192, 512, 512);
    ln_f32<<<dim3(2048), blk, 0, stream>>>(dout, out, ln2g, ln2b, nullptr);
}

// Round 16
// 1853.783 us; speedup vs baseline: 2.6246x; 2.5543x over previous
//
#include <hip/hip_runtime.h>
#include <math.h>

// B=16, T=512, F=512, H=8, D=64; rows = B*T = 8192
#define GRID_WGS 128   // launched WGs for GRU; 8 elected (same XCD) participate

typedef __attribute__((ext_vector_type(8))) short bf16x8;
typedef __attribute__((ext_vector_type(4))) float f32x4;
typedef __attribute__((ext_vector_type(4))) unsigned short us4;

static __device__ __forceinline__ float sigmoidf_(float x) {
    return 1.0f / (1.0f + __expf(-x));
}
static __device__ __forceinline__ unsigned short f2bf(float f) {
    unsigned int u = __float_as_uint(f);
    u += 0x7fffu + ((u >> 16) & 1u);
    return (unsigned short)(u >> 16);
}
static __device__ __forceinline__ float bfbits2f(unsigned int b) {
    return __uint_as_float(b << 16);
}
static __device__ __forceinline__ void gload_lds16(const void* g, void* l) {
    __builtin_amdgcn_global_load_lds(
        (const __attribute__((address_space(1))) unsigned int*)g,
        (__attribute__((address_space(3))) unsigned int*)l, 16, 0, 0);
}

// ---------------- prep: f2bf(x) + bias concat + 6 weight transposes + zero hbuf/Z -------------
__global__ __launch_bounds__(256)
void prep(const float* __restrict__ x, unsigned short* __restrict__ xb,
          const float* __restrict__ bq, const float* __restrict__ bk,
          const float* __restrict__ bv, float* __restrict__ bqkv,
          const float* __restrict__ Wq, const float* __restrict__ Wk,
          const float* __restrict__ Wv, const float* __restrict__ Wo,
          const float* __restrict__ gruk, const float* __restrict__ Wd,
          unsigned short* __restrict__ wqkvT, unsigned short* __restrict__ woT,
          unsigned short* __restrict__ gkT, unsigned short* __restrict__ wdT,
          unsigned int* __restrict__ hbufz, unsigned int* __restrict__ Z)
{
    __shared__ float tile[32][33];
    const int bid = blockIdx.x, tid = threadIdx.x;
    if (bid < 4096) {
        const int i = (bid * 256 + tid) * 4;
        const float4 v = *(const float4*)(x + i);
        const us4 o = {f2bf(v.x), f2bf(v.y), f2bf(v.z), f2bf(v.w)};
        *(us4*)(xb + i) = o;
    } else if (bid < 4102) {
        const int i = (bid - 4096) * 256 + tid;
        bqkv[i] = (i < 512) ? bq[i] : ((i < 1024) ? bk[i - 512] : bv[i - 1024]);
    } else if (bid < 6150) {
        int t = bid - 4102;
        const float* in; unsigned short* out; int N;
        if      (t < 256)  { in = Wq;   out = wqkvT;               N = 512;  }
        else if (t < 512)  { in = Wk;   out = wqkvT + 256 * 1024;  N = 512;  t -= 256;  }
        else if (t < 768)  { in = Wv;   out = wqkvT + 512 * 1024;  N = 512;  t -= 512;  }
        else if (t < 1024) { in = Wo;   out = woT;                 N = 512;  t -= 768;  }
        else if (t < 1792) { in = gruk; out = gkT;                 N = 1536; t -= 1024; }
        else               { in = Wd;   out = wdT;                 N = 512;  t -= 1792; }
        const int tilesx = N / 32;
        const int n0 = (t % tilesx) * 32, k0 = (t / tilesx) * 32;
        const int c = tid & 31, r8 = tid >> 5;
#pragma unroll
        for (int i = 0; i < 4; ++i) {
            const int k = r8 + i * 8;
            tile[k][c] = in[(size_t)(k0 + k) * N + n0 + c];
        }
        __syncthreads();
#pragma unroll
        for (int i = 0; i < 4; ++i) {
            const int n = r8 + i * 8;
            out[(size_t)(n0 + n) * 512 + k0 + c] = f2bf(tile[c][n]);
        }
    } else if (bid == 6150) {
        for (int i = tid; i < 8192; i += 256) hbufz[i] = 0u;
    } else {
        for (int i = tid; i < 2048; i += 256) Z[i] = 0u;
    }
}

// ---------------- bf16 MFMA GEMM: C=A@Bt (+bias)(+resid); f32 C and/or bf16 Cb outputs --------
__global__ __launch_bounds__(256)
void gemm_bf16(const unsigned short* __restrict__ A, const unsigned short* __restrict__ Bt,
               const float* __restrict__ bias, const float* __restrict__ resid,
               float* __restrict__ C, unsigned short* __restrict__ Cb,
               int M, int N, int K)
{
    __shared__ unsigned short As[128 * 64];
    __shared__ unsigned short Bs[128 * 64];
    const int tid = threadIdx.x;
    const int wave = tid >> 6, lane = tid & 63;
    const int bm = blockIdx.x * 128, bn = blockIdx.y * 128;
    const int wr = wave >> 1, wc = wave & 1;
    const int stR = lane >> 3;
    const int stC = (lane & 7) * 8;

    const unsigned short* Abase = A + (size_t)(bm + wave * 32 + stR) * K + stC;
    const unsigned short* Bbase = Bt + (size_t)(bn + wave * 32 + stR) * K + stC;
    unsigned short* AsW = As + wave * 2048;
    unsigned short* BsW = Bs + wave * 2048;

    f32x4 acc[4][4] = {};
    const int fr = lane & 15;
    const int fko = (lane >> 4) * 8;

    for (int k0 = 0; k0 < K; k0 += 64) {
#pragma unroll
        for (int i = 0; i < 4; ++i) {
            gload_lds16(Abase + (size_t)i * 8 * K + k0, AsW + i * 512);
            gload_lds16(Bbase + (size_t)i * 8 * K + k0, BsW + i * 512);
        }
        __syncthreads();
        bf16x8 af[4][2], bfr[4][2];
#pragma unroll
        for (int m = 0; m < 4; ++m) {
            const unsigned short* ap = As + (wr * 64 + m * 16 + fr) * 64 + fko;
            af[m][0] = *(const bf16x8*)(ap);
            af[m][1] = *(const bf16x8*)(ap + 32);
        }
#pragma unroll
        for (int n = 0; n < 4; ++n) {
            const unsigned short* bp = Bs + (wc * 64 + n * 16 + fr) * 64 + fko;
            bfr[n][0] = *(const bf16x8*)(bp);
            bfr[n][1] = *(const bf16x8*)(bp + 32);
        }
#pragma unroll
        for (int m = 0; m < 4; ++m)
#pragma unroll
            for (int n = 0; n < 4; ++n) {
                acc[m][n] = __builtin_amdgcn_mfma_f32_16x16x32_bf16(af[m][0], bfr[n][0], acc[m][n], 0, 0, 0);
                acc[m][n] = __builtin_amdgcn_mfma_f32_16x16x32_bf16(af[m][1], bfr[n][1], acc[m][n], 0, 0, 0);
            }
        __syncthreads();
    }
    const int fq = lane >> 4;
#pragma unroll
    for (int n = 0; n < 4; ++n) {
        const int col = bn + wc * 64 + n * 16 + fr;
        const float bv = bias ? bias[col] : 0.f;
#pragma unroll
        for (int m = 0; m < 4; ++m) {
#pragma unroll
            for (int j = 0; j < 4; ++j) {
                const int row = bm + wr * 64 + m * 16 + fq * 4 + j;
                float v = acc[m][n][j] + bv;
                if (resid) v += resid[(size_t)row * N + col];
                if (C)  C[(size_t)row * N + col] = v;
                if (Cb) Cb[(size_t)row * N + col] = f2bf(v);
            }
        }
    }
}

// ---------------- MFMA attention (r13 proven): 32 q-rows/block, 2 waves -----------------------
__global__ __launch_bounds__(128)
void attn_mfma(const unsigned short* __restrict__ qkv, unsigned short* __restrict__ ctxb)
{
    __shared__ unsigned short P[32][520];
    __shared__ unsigned short KV[64][72];
    __shared__ float invs[32];
    const int tid = threadIdx.x;
    const int wg = blockIdx.x;
    const int qt = wg & 15, h = (wg >> 4) & 7, b = wg >> 7;
    const int t0 = qt * 32;
    const int w = tid >> 6, lane = tid & 63;
    const int lo16 = lane & 15, hi4 = lane >> 4;

    bf16x8 Aq0, Aq1;
    {
        const unsigned short* qrow =
            qkv + ((size_t)(b * 512 + t0 + w * 16 + lo16)) * 1536 + h * 64 + hi4 * 8;
        Aq0 = *(const bf16x8*)(qrow);
        Aq1 = *(const bf16x8*)(qrow + 32);
    }
    const int ss = tid >> 1, sh = tid & 1;

    for (int st = 0; st < 8; ++st) {
        {
            const unsigned short* krow =
                qkv + ((size_t)(b * 512 + st * 64 + ss)) * 1536 + 512 + h * 64 + sh * 32;
            *(bf16x8*)&KV[ss][sh * 32]      = *(const bf16x8*)(krow);
            *(bf16x8*)&KV[ss][sh * 32 + 8]  = *(const bf16x8*)(krow + 8);
            *(bf16x8*)&KV[ss][sh * 32 + 16] = *(const bf16x8*)(krow + 16);
            *(bf16x8*)&KV[ss][sh * 32 + 24] = *(const bf16x8*)(krow + 24);
        }
        __syncthreads();
#pragma unroll
        for (int n = 0; n < 4; ++n) {
            const bf16x8 b0 = *(const bf16x8*)&KV[n * 16 + lo16][hi4 * 8];
            const bf16x8 b1 = *(const bf16x8*)&KV[n * 16 + lo16][32 + hi4 * 8];
            f32x4 acc = {0.f, 0.f, 0.f, 0.f};
            acc = __builtin_amdgcn_mfma_f32_16x16x32_bf16(Aq0, b0, acc, 0, 0, 0);
            acc = __builtin_amdgcn_mfma_f32_16x16x32_bf16(Aq1, b1, acc, 0, 0, 0);
#pragma unroll
            for (int j = 0; j < 4; ++j)
                P[w * 16 + hi4 * 4 + j][st * 64 + n * 16 + lo16] = f2bf(acc[j]);
        }
        __syncthreads();
    }
    {
        const int r = tid >> 2, quad = tid & 3;
        const int c0 = quad * 128;
        float mx = -1e30f;
#pragma unroll
        for (int c8 = 0; c8 < 16; ++c8) {
            const bf16x8 sv = *(const bf16x8*)&P[r][c0 + c8 * 8];
#pragma unroll
            for (int e = 0; e < 8; ++e) mx = fmaxf(mx, bfbits2f((unsigned short)sv[e]));
        }
        mx = fmaxf(mx, __shfl_xor(mx, 1));
        mx = fmaxf(mx, __shfl_xor(mx, 2));
        mx *= 0.125f;
        float sum = 0.f;
#pragma unroll
        for (int c8 = 0; c8 < 16; ++c8) {
            const bf16x8 sv = *(const bf16x8*)&P[r][c0 + c8 * 8];
            us4 o1, o2;
#pragma unroll
            for (int e = 0; e < 8; ++e) {
                const float p = __expf(bfbits2f((unsigned short)sv[e]) * 0.125f - mx);
                sum += p;
                if (e < 4) o1[e] = f2bf(p); else o2[e - 4] = f2bf(p);
            }
            *(us4*)&P[r][c0 + c8 * 8] = o1;
            *(us4*)&P[r][c0 + c8 * 8 + 4] = o2;
        }
        sum += __shfl_xor(sum, 1);
        sum += __shfl_xor(sum, 2);
        if (quad == 0) invs[r] = 1.0f / sum;
    }
    __syncthreads();
    f32x4 oac[4] = {};
    for (int st = 0; st < 8; ++st) {
        {
            const unsigned short* vrow =
                qkv + ((size_t)(b * 512 + st * 64 + ss)) * 1536 + 1024 + h * 64 + sh * 32;
            const bf16x8 v0 = *(const bf16x8*)(vrow);
            const bf16x8 v1 = *(const bf16x8*)(vrow + 8);
            const bf16x8 v2 = *(const bf16x8*)(vrow + 16);
            const bf16x8 v3 = *(const bf16x8*)(vrow + 24);
#pragma unroll
            for (int e = 0; e < 8; ++e) {
                KV[sh * 32 + e][ss]      = (unsigned short)v0[e];
                KV[sh * 32 + 8 + e][ss]  = (unsigned short)v1[e];
                KV[sh * 32 + 16 + e][ss] = (unsigned short)v2[e];
                KV[sh * 32 + 24 + e][ss] = (unsigned short)v3[e];
            }
        }
        __syncthreads();
        const bf16x8 pa0 = *(const bf16x8*)&P[w * 16 + lo16][st * 64 + hi4 * 8];
        const bf16x8 pa1 = *(const bf16x8*)&P[w * 16 + lo16][st * 64 + 32 + hi4 * 8];
#pragma unroll
        for (int n = 0; n < 4; ++n) {
            const bf16x8 b0 = *(const bf16x8*)&KV[n * 16 + lo16][hi4 * 8];
            const bf16x8 b1 = *(const bf16x8*)&KV[n * 16 + lo16][32 + hi4 * 8];
            oac[n] = __builtin_amdgcn_mfma_f32_16x16x32_bf16(pa0, b0, oac[n], 0, 0, 0);
            oac[n] = __builtin_amdgcn_mfma_f32_16x16x32_bf16(pa1, b1, oac[n], 0, 0, 0);
        }
        __syncthreads();
    }
#pragma unroll
    for (int n = 0; n < 4; ++n) {
#pragma unroll
        for (int j = 0; j < 4; ++j) {
            const int q = w * 16 + hi4 * 4 + j;
            ctxb[((size_t)(b * 512 + t0 + q)) * 512 + h * 64 + n * 16 + lo16] =
                f2bf(oac[n][j] * invs[q]);
        }
    }
}

// ---------------- layernorm (rows of 512), optional bf16 side output --------------------------
__global__ __launch_bounds__(256)
void ln_f32(const float* __restrict__ in, float* __restrict__ out,
            const float* __restrict__ g, const float* __restrict__ bb,
            unsigned short* __restrict__ outb)
{
    const int lane = threadIdx.x & 63;
    const int row = blockIdx.x * 4 + (threadIdx.x >> 6);
    const float* x = in + (size_t)row * 512;
    const float4 a = *(const float4*)(x + lane * 4);
    const float4 c = *(const float4*)(x + 256 + lane * 4);
    float s = a.x + a.y + a.z + a.w + c.x + c.y + c.z + c.w;
#pragma unroll
    for (int off = 1; off < 64; off <<= 1) s += __shfl_xor(s, off);
    const float mu = s * (1.0f / 512.0f);
    float vs = 0.f;
    vs += (a.x - mu) * (a.x - mu) + (a.y - mu) * (a.y - mu);
    vs += (a.z - mu) * (a.z - mu) + (a.w - mu) * (a.w - mu);
    vs += (c.x - mu) * (c.x - mu) + (c.y - mu) * (c.y - mu);
    vs += (c.z - mu) * (c.z - mu) + (c.w - mu) * (c.w - mu);
#pragma unroll
    for (int off = 1; off < 64; off <<= 1) vs += __shfl_xor(vs, off);
    const float rstd = rsqrtf(vs * (1.0f / 512.0f) + 1e-3f);
    const float4 g1 = *(const float4*)(g + lane * 4);
    const float4 g2 = *(const float4*)(g + 256 + lane * 4);
    const float4 b1 = *(const float4*)(bb + lane * 4);
    const float4 b2 = *(const float4*)(bb + 256 + lane * 4);
    float* y = out + (size_t)row * 512;
    const float4 o1 = {(a.x - mu) * rstd * g1.x + b1.x, (a.y - mu) * rstd * g1.y + b1.y,
                       (a.z - mu) * rstd * g1.z + b1.z, (a.w - mu) * rstd * g1.w + b1.w};
    const float4 o2 = {(c.x - mu) * rstd * g2.x + b2.x, (c.y - mu) * rstd * g2.y + b2.y,
                       (c.z - mu) * rstd * g2.z + b2.z, (c.w - mu) * rstd * g2.w + b2.w};
    *(float4*)(y + lane * 4) = o1;
    *(float4*)(y + 256 + lane * 4) = o2;
    if (outb) {
        unsigned short* yb = outb + (size_t)row * 512;
        const us4 p1 = {f2bf(o1.x), f2bf(o1.y), f2bf(o1.z), f2bf(o1.w)};
        const us4 p2 = {f2bf(o2.x), f2bf(o2.y), f2bf(o2.z), f2bf(o2.w)};
        *(us4*)(yb + lane * 4) = p1;
        *(us4*)(yb + 256 + lane * 4) = p2;
    }
}

// ---------------- persistent GRU, XCD-pinned (r13 exact: proven best, 220 VGPR) ---------------
__global__ __launch_bounds__(256, 1)
void gru_persist(const float* __restrict__ rk,
                 const unsigned short* __restrict__ xpb,
                 const float* __restrict__ rb,
                 unsigned short* __restrict__ hbuf,
                 unsigned short* __restrict__ goutb,
                 unsigned int* __restrict__ bar,
                 unsigned int* __restrict__ ctl)
{
    __shared__ int sh_part, sh_memb;
    const int tid = threadIdx.x;

    if (tid == 0) {
        unsigned int xcc;
        asm("s_getreg_b32 %0, hwreg(HW_REG_XCC_ID)" : "=s"(xcc));
        xcc &= 7u;
        const unsigned int rank =
            __hip_atomic_fetch_add(&ctl[xcc], 1u, __ATOMIC_RELAXED, __HIP_MEMORY_SCOPE_AGENT);
        __hip_atomic_fetch_add(&ctl[8], 1u, __ATOMIC_ACQ_REL, __HIP_MEMORY_SCOPE_AGENT);
        unsigned int spins = 0;
        while (__hip_atomic_load(&ctl[8], __ATOMIC_ACQUIRE, __HIP_MEMORY_SCOPE_AGENT)
               < (unsigned)GRID_WGS) {
            __builtin_amdgcn_s_sleep(1);
            if (++spins > (1u << 20)) break;
        }
        unsigned int cnt[8];
#pragma unroll
        for (int i = 0; i < 8; ++i)
            cnt[i] = __hip_atomic_load(&ctl[i], __ATOMIC_ACQUIRE, __HIP_MEMORY_SCOPE_AGENT);
        int best = 0;
#pragma unroll
        for (int i = 1; i < 8; ++i)
            if (cnt[i] > cnt[best]) best = i;
        sh_part = (xcc == (unsigned)best && rank < 8u) ? 1 : 0;
        sh_memb = (int)rank;
    }
    __syncthreads();
    if (!sh_part) return;
    const int member = sh_memb;

    const int wv = tid >> 6, l = tid & 63;
    const int wgi = member * 4 + wv;
    const int lo16 = l & 15;
    const int hi4 = l >> 4;
    const int gc = wgi * 16 + lo16;

    bf16x8 B[3][16];
#pragma unroll
    for (int g = 0; g < 3; ++g)
#pragma unroll
        for (int kt = 0; kt < 16; ++kt) {
            bf16x8 bv;
#pragma unroll
            for (int j = 0; j < 8; ++j) {
                const int k = kt * 32 + hi4 * 8 + j;
                bv[j] = (short)f2bf(rk[(size_t)k * 1536 + g * 512 + gc]);
            }
            B[g][kt] = bv;
        }
    const float rbz = rb[gc], rbr = rb[512 + gc], rbh = rb[1024 + gc];
    float hst[4] = {0.f, 0.f, 0.f, 0.f};

    float xz[4], xr[4], xh[4];
#pragma unroll
    for (int j = 0; j < 4; ++j) {
        const unsigned short* xrow = xpb + ((size_t)((hi4 * 4 + j) * 512)) * 1536 + gc;
        xz[j] = bfbits2f(xrow[0]); xr[j] = bfbits2f(xrow[512]); xh[j] = bfbits2f(xrow[1024]);
    }
    unsigned int hnb[4] = {0u, 0u, 0u, 0u};

    const unsigned short* ab0 = hbuf + lo16 * 512 + hi4 * 8;
    const unsigned short* ab1 = ab0 + 16 * 512;

    for (int t = 0; t < 512; ++t) {
        const unsigned short* abase = (t & 1) ? ab1 : ab0;
        unsigned short* hw = hbuf + (size_t)((t + 1) & 1) * (16 * 512);
        bf16x8 A[16];
        asm volatile(
            "global_load_dwordx4 %0,  %16, off sc0\n\t"
            "global_load_dwordx4 %1,  %16, off offset:64 sc0\n\t"
            "global_load_dwordx4 %2,  %16, off offset:128 sc0\n\t"
            "global_load_dwordx4 %3,  %16, off offset:192 sc0\n\t"
            "global_load_dwordx4 %4,  %16, off offset:256 sc0\n\t"
            "global_load_dwordx4 %5,  %16, off offset:320 sc0\n\t"
            "global_load_dwordx4 %6,  %16, off offset:384 sc0\n\t"
            "global_load_dwordx4 %7,  %16, off offset:448 sc0\n\t"
            "global_load_dwordx4 %8,  %16, off offset:512 sc0\n\t"
            "global_load_dwordx4 %9,  %16, off offset:576 sc0\n\t"
            "global_load_dwordx4 %10, %16, off offset:640 sc0\n\t"
            "global_load_dwordx4 %11, %16, off offset:704 sc0\n\t"
            "global_load_dwordx4 %12, %16, off offset:768 sc0\n\t"
            "global_load_dwordx4 %13, %16, off offset:832 sc0\n\t"
            "global_load_dwordx4 %14, %16, off offset:896 sc0\n\t"
            "global_load_dwordx4 %15, %16, off offset:960 sc0"
            : "=&v"(A[0]), "=&v"(A[1]), "=&v"(A[2]), "=&v"(A[3]),
              "=&v"(A[4]), "=&v"(A[5]), "=&v"(A[6]), "=&v"(A[7]),
              "=&v"(A[8]), "=&v"(A[9]), "=&v"(A[10]), "=&v"(A[11]),
              "=&v"(A[12]), "=&v"(A[13]), "=&v"(A[14]), "=&v"(A[15])
            : "v"(abase) : "memory");
        unsigned int xnz[4], xnr[4], xnh[4];
        {
            const unsigned short* x0 = xpb + ((size_t)((hi4 * 4 + 0) * 512 + t + 1)) * 1536 + gc;
            const unsigned short* x1 = xpb + ((size_t)((hi4 * 4 + 1) * 512 + t + 1)) * 1536 + gc;
            const unsigned short* x2 = xpb + ((size_t)((hi4 * 4 + 2) * 512 + t + 1)) * 1536 + gc;
            const unsigned short* x3 = xpb + ((size_t)((hi4 * 4 + 3) * 512 + t + 1)) * 1536 + gc;
            asm volatile(
                "global_load_ushort %0,  %12, off\n\t"
                "global_load_ushort %1,  %12, off offset:1024\n\t"
                "global_load_ushort %2,  %12, off offset:2048\n\t"
                "global_load_ushort %3,  %13, off\n\t"
                "global_load_ushort %4,  %13, off offset:1024\n\t"
                "global_load_ushort %5,  %13, off offset:2048\n\t"
                "global_load_ushort %6,  %14, off\n\t"
                "global_load_ushort %7,  %14, off offset:1024\n\t"
                "global_load_ushort %8,  %14, off offset:2048\n\t"
                "global_load_ushort %9,  %15, off\n\t"
                "global_load_ushort %10, %15, off offset:1024\n\t"
                "global_load_ushort %11, %15, off offset:2048"
                : "=&v"(xnz[0]), "=&v"(xnr[0]), "=&v"(xnh[0]),
                  "=&v"(xnz[1]), "=&v"(xnr[1]), "=&v"(xnh[1]),
                  "=&v"(xnz[2]), "=&v"(xnr[2]), "=&v"(xnh[2]),
                  "=&v"(xnz[3]), "=&v"(xnr[3]), "=&v"(xnh[3])
                : "v"(x0), "v"(x1), "v"(x2), "v"(x3) : "memory");
        }
        {
            const int grow = t ? t - 1 : 0;
            unsigned short* g0 = goutb + ((size_t)((hi4 * 4 + 0) * 512 + grow)) * 512 + gc;
            unsigned short* g1 = goutb + ((size_t)((hi4 * 4 + 1) * 512 + grow)) * 512 + gc;
            unsigned short* g2 = goutb + ((size_t)((hi4 * 4 + 2) * 512 + grow)) * 512 + gc;
            unsigned short* g3 = goutb + ((size_t)((hi4 * 4 + 3) * 512 + grow)) * 512 + gc;
            asm volatile(
                "global_store_short %0, %4, off\n\t"
                "global_store_short %1, %5, off\n\t"
                "global_store_short %2, %6, off\n\t"
                "global_store_short %3, %7, off"
                :: "v"(g0), "v"(g1), "v"(g2), "v"(g3),
                   "v"(hnb[0]), "v"(hnb[1]), "v"(hnb[2]), "v"(hnb[3]) : "memory");
        }
        asm volatile("s_waitcnt vmcnt(16)" ::: "memory");
        __builtin_amdgcn_sched_barrier(0);

        f32x4 accz = {0.f, 0.f, 0.f, 0.f};
        f32x4 accr = {0.f, 0.f, 0.f, 0.f};
        f32x4 acch = {0.f, 0.f, 0.f, 0.f};
#pragma unroll
        for (int kt = 0; kt < 16; ++kt) {
            accz = __builtin_amdgcn_mfma_f32_16x16x32_bf16(A[kt], B[0][kt], accz, 0, 0, 0);
            accr = __builtin_amdgcn_mfma_f32_16x16x32_bf16(A[kt], B[1][kt], accr, 0, 0, 0);
            acch = __builtin_amdgcn_mfma_f32_16x16x32_bf16(A[kt], B[2][kt], acch, 0, 0, 0);
        }
#pragma unroll
        for (int j = 0; j < 4; ++j) {
            const int b = hi4 * 4 + j;
            const float z = sigmoidf_(xz[j] + accz[j] + rbz);
            const float r = sigmoidf_(xr[j] + accr[j] + rbr);
            const float hh = fmaxf(xh[j] + r * (acch[j] + rbh), 0.f);
            const float hnew = z * hst[j] + (1.f - z) * hh;
            hst[j] = hnew;
            const unsigned short hb = f2bf(hnew);
            hnb[j] = (unsigned int)hb;
            hw[b * 512 + gc] = hb;
        }
        asm volatile("s_waitcnt vmcnt(0)" ::: "memory");
        __builtin_amdgcn_sched_barrier(0);
#pragma unroll
        for (int j = 0; j < 4; ++j) {
            xz[j] = bfbits2f(xnz[j]); xr[j] = bfbits2f(xnr[j]); xh[j] = bfbits2f(xnh[j]);
        }
        if (t < 511) {
            __syncthreads();
            if (tid == 0) {
                __hip_atomic_fetch_add(bar, 1u, __ATOMIC_RELAXED, __HIP_MEMORY_SCOPE_AGENT);
                const unsigned int target = 8u * (unsigned int)(t + 1);
                unsigned int it = 0;
                while (__hip_atomic_load(bar, __ATOMIC_RELAXED, __HIP_MEMORY_SCOPE_AGENT)
                       < target) {
                    if (++it > (1u << 14)) break;
                }
                if (it > (1u << 14)) {
                    unsigned int cur = 0, it2 = 0;
                    do {
                        asm volatile("global_atomic_add %0, %1, %2, off sc0\n\t"
                                     "s_waitcnt vmcnt(0)"
                                     : "=v"(cur) : "v"(bar), "v"(0u) : "memory");
                        if (++it2 > (1u << 15)) break;
                    } while (cur < target);
                }
            }
            __syncthreads();
        }
    }
#pragma unroll
    for (int j = 0; j < 4; ++j)
        goutb[((size_t)((hi4 * 4 + j) * 512 + 511)) * 512 + gc] = (unsigned short)hnb[j];
}

extern "C" void kernel_launch(void* const* d_in, const int* in_sizes, int n_in,
                              void* d_out, int out_size, void* d_ws, size_t ws_size,
                              hipStream_t stream)
{
    const float* x     = (const float*)d_in[0];
    const float* Wq    = (const float*)d_in[1];
    const float* bq    = (const float*)d_in[2];
    const float* Wk    = (const float*)d_in[3];
    const float* bk    = (const float*)d_in[4];
    const float* Wv    = (const float*)d_in[5];
    const float* bv    = (const float*)d_in[6];
    const float* Wo    = (const float*)d_in[7];
    const float* bo    = (const float*)d_in[8];
    const float* ln1g  = (const float*)d_in[9];
    const float* ln1b  = (const float*)d_in[10];
    const float* gruk  = (const float*)d_in[11];
    const float* grurk = (const float*)d_in[12];
    const float* grub  = (const float*)d_in[13];
    const float* Wd    = (const float*)d_in[14];
    const float* bd    = (const float*)d_in[15];
    const float* ln2g  = (const float*)d_in[16];
    const float* ln2b  = (const float*)d_in[17];
    float* out = (float*)d_out;

    char* base = (char*)d_ws;
    const size_t MB = 1024 * 1024;
    unsigned short* qkvb = (unsigned short*)base;
    unsigned short* xpb  = (unsigned short*)base;
    float*          dout = (float*)(base + 24 * MB);
    float*          R4   = (float*)(base + 48 * MB);
    unsigned short* S1   = (unsigned short*)(base + 64 * MB);
    unsigned short* WT   = (unsigned short*)(base + 72 * MB);
    unsigned short* wqkvT = WT;
    unsigned short* woT  = WT + 768 * 1024;
    unsigned short* gkT  = WT + 1024 * 1024;
    unsigned short* wdT  = WT + 1792 * 1024;
    unsigned short* hbuf = (unsigned short*)(base + 76 * MB);
    char*           Z    = base + 76 * MB + 64 * 1024;
    unsigned int*   ctl  = (unsigned int*)(Z);
    unsigned int*   bar  = (unsigned int*)(Z + 256);
    float*          bqkv = (float*)(base + 77 * MB);

    const dim3 blk(256);
    const dim3 g512(8192 / 128, 512 / 128);
    const dim3 g1536(8192 / 128, 1536 / 128);

    prep<<<dim3(6152), blk, 0, stream>>>(x, S1, bq, bk, bv, bqkv,
                                         Wq, Wk, Wv, Wo, gruk, Wd,
                                         wqkvT, woT, gkT, wdT,
                                         (unsigned int*)hbuf, (unsigned int*)Z);
    gemm_bf16<<<g1536, blk, 0, stream>>>(S1, wqkvT, bqkv, nullptr, nullptr, qkvb, 8192, 1536, 512);
    attn_mfma<<<dim3(2048), dim3(128), 0, stream>>>(qkvb, S1);
    gemm_bf16<<<g512, blk, 0, stream>>>(S1, woT, bo, x, R4, nullptr, 8192, 512, 512);
    ln_f32<<<dim3(2048), blk, 0, stream>>>(R4, R4, ln1g, ln1b, S1);
    gemm_bf16<<<g1536, blk, 0, stream>>>(S1, gkT, grub, nullptr, nullptr, xpb, 8192, 1536, 512);
    gru_persist<<<dim3(GRID_WGS), blk, 0, stream>>>(grurk, xpb, grub + 1536, hbuf, S1, bar, ctl);
    gemm_bf16<<<g512, blk, 0, stream>>>(S1, wdT, bd, R4, dout, nullptr, 8192, 512, 512);
    ln_f32<<<dim3(2048), blk, 0, stream>>>(dout, out, ln2g, ln2b, nullptr);
}